// Round 4
// baseline (31.513 us; speedup 1.0000x reference)
//
#include <hip/hip_runtime.h>

#define H_DIM 1024
#define H4 (H_DIM / 4)   // float4 elements per row = 256
#define WPB 8            // words per block

typedef float f32x4 __attribute__((ext_vector_type(4)));

// 1024 blocks x 256 threads. Each block owns WPB=8 consecutive words; each
// thread owns one float4 (16B) slot of the H=1024 row. Span discovery:
// gallop-from-proportional-guess binary search (~2-4 dependent loads for
// near-uniform spans) for the block's first word, then wave-parallel span
// counting via one 64-lane seg load + __ballot/popcount (scalar-scan
// fallback if the 8 words span >64 tokens). x read-once / out write-once ->
// non-temporal.
__global__ void __launch_bounds__(256)
WordPooling_fused_kernel(const float* __restrict__ x,
                         const int* __restrict__ seg,
                         int n_tokens, int W,
                         float* __restrict__ out) {
    int w0 = blockIdx.x * WPB;
    int h = threadIdx.x;
    int lane = threadIdx.x & 63;

    // ---- st = lower_bound(seg, w0): first token with seg[t] >= w0 ----
    int st = 0;
    if (w0 > 0) {
        int g = (int)((long long)w0 * n_tokens / W);   // proportional guess
        if (g > n_tokens - 1) g = n_tokens - 1;
        int lo, hi;  // invariant: seg[lo] < w0 (lo==-1 sentinel), seg[hi] >= w0 (hi==n sentinel)
        if (seg[g] >= w0) {
            int step = 1;
            while (step <= g && seg[g - step] >= w0) step <<= 1;
            lo = (step <= g) ? g - step : -1;
            hi = g - (step >> 1);
        } else {
            int step = 1;
            while (g + step < n_tokens && seg[g + step] < w0) step <<= 1;
            lo = g + (step >> 1);
            hi = (g + step < n_tokens) ? g + step : n_tokens;
        }
        while (hi - lo > 1) {
            int mid = (lo + hi) >> 1;
            if (seg[mid] < w0) lo = mid; else hi = mid;
        }
        st = hi;
    }

    int wlast = w0 + WPB - 1;
    if (wlast > W - 1) wlast = W - 1;

    // ---- wave-parallel span counts over a 64-token window ----
    int idx = st + lane;
    int sv = (idx < n_tokens) ? seg[idx] : 0x7FFFFFFF;
    bool windowed = (__ballot(sv > wlast) != 0ULL);  // all owned tokens inside window

    const f32x4* x4 = (const f32x4*)x;
    f32x4* out4 = (f32x4*)out;

    int cur = st;
    for (int w = w0; w <= wlast; ++w) {
        int cnt;
        if (windowed) {
            cnt = (int)__popcll(__ballot(sv == w));
        } else {
            cnt = 0;  // generic fallback: dependent scalar scan
            while (cur + cnt < n_tokens && seg[cur + cnt] == w) ++cnt;
        }
        const f32x4* p = x4 + (size_t)cur * H4 + h;
        f32x4 acc;
        if (cnt == 4) {
            f32x4 v0 = __builtin_nontemporal_load(p);
            f32x4 v1 = __builtin_nontemporal_load(p + H4);
            f32x4 v2 = __builtin_nontemporal_load(p + 2 * H4);
            f32x4 v3 = __builtin_nontemporal_load(p + 3 * H4);
            acc = (((v0 + v1) + v2) + v3) * 0.25f;
        } else {
            acc = (f32x4)(0.0f);
            for (int i = 0; i < cnt; ++i)
                acc += __builtin_nontemporal_load(p + (size_t)i * H4);
            acc *= 1.0f / fmaxf((float)cnt, 1.0f);
        }
        __builtin_nontemporal_store(acc, out4 + (size_t)w * H4 + h);
        cur += cnt;
    }
}

extern "C" void kernel_launch(void* const* d_in, const int* in_sizes, int n_in,
                              void* d_out, int out_size, void* d_ws, size_t ws_size,
                              hipStream_t stream) {
    const float* x  = (const float*)d_in[0];
    const int* seg  = (const int*)d_in[1];
    int n_tokens    = in_sizes[1];          // B*S = 32768
    int W           = out_size / H_DIM;     // num_segments = 8192

    int grid = (W + WPB - 1) / WPB;
    WordPooling_fused_kernel<<<grid, H4, 0, stream>>>(x, seg, n_tokens, W, (float*)d_out);
}

// Round 5
// 30.726 us; speedup vs baseline: 1.0256x; 1.0256x over previous
//
#include <hip/hip_runtime.h>

#define H_DIM 1024
#define H4 (H_DIM / 4)   // float4 elements per row = 256
#define WPB 8            // words per block

typedef float f32x4 __attribute__((ext_vector_type(4)));

// 1024 blocks x 256 threads. Each block owns WPB=8 consecutive words; each
// thread owns one float4 (16B) slot of the H=1024 row. Span discovery:
// gallop-from-proportional-guess binary search for the block's first word,
// then wave-parallel span counting via one 64-lane seg load + __ballot
// (scalar-scan fallback if the 8 words span >64 tokens).
// NOTE: loads/stores are CACHED (no nt) on purpose — the 160 MiB steady-state
// working set fits the 256 MiB Infinity Cache across graph replays; nt hints
// were forcing an HBM re-stream every call.
__global__ void __launch_bounds__(256)
WordPooling_fused_kernel(const float* __restrict__ x,
                         const int* __restrict__ seg,
                         int n_tokens, int W,
                         float* __restrict__ out) {
    int w0 = blockIdx.x * WPB;
    int h = threadIdx.x;
    int lane = threadIdx.x & 63;

    // ---- st = lower_bound(seg, w0): first token with seg[t] >= w0 ----
    int st = 0;
    if (w0 > 0) {
        int g = (int)((long long)w0 * n_tokens / W);   // proportional guess
        if (g > n_tokens - 1) g = n_tokens - 1;
        int lo, hi;  // invariant: seg[lo] < w0 (lo==-1), seg[hi] >= w0 (hi==n)
        if (seg[g] >= w0) {
            int step = 1;
            while (step <= g && seg[g - step] >= w0) step <<= 1;
            lo = (step <= g) ? g - step : -1;
            hi = g - (step >> 1);
        } else {
            int step = 1;
            while (g + step < n_tokens && seg[g + step] < w0) step <<= 1;
            lo = g + (step >> 1);
            hi = (g + step < n_tokens) ? g + step : n_tokens;
        }
        while (hi - lo > 1) {
            int mid = (lo + hi) >> 1;
            if (seg[mid] < w0) lo = mid; else hi = mid;
        }
        st = hi;
    }

    int wlast = w0 + WPB - 1;
    if (wlast > W - 1) wlast = W - 1;

    // ---- wave-parallel span counts over a 64-token window ----
    int idx = st + lane;
    int sv = (idx < n_tokens) ? seg[idx] : 0x7FFFFFFF;
    bool windowed = (__ballot(sv > wlast) != 0ULL);  // all owned tokens inside window

    const f32x4* x4 = (const f32x4*)x;
    f32x4* out4 = (f32x4*)out;

    int cur = st;
    for (int w = w0; w <= wlast; ++w) {
        int cnt;
        if (windowed) {
            cnt = (int)__popcll(__ballot(sv == w));
        } else {
            cnt = 0;  // generic fallback: dependent scalar scan
            while (cur + cnt < n_tokens && seg[cur + cnt] == w) ++cnt;
        }
        const f32x4* p = x4 + (size_t)cur * H4 + h;
        f32x4 acc;
        if (cnt == 4) {
            f32x4 v0 = p[0];
            f32x4 v1 = p[H4];
            f32x4 v2 = p[2 * H4];
            f32x4 v3 = p[3 * H4];
            acc = (((v0 + v1) + v2) + v3) * 0.25f;
        } else {
            acc = (f32x4)(0.0f);
            for (int i = 0; i < cnt; ++i)
                acc += p[(size_t)i * H4];
            acc *= 1.0f / fmaxf((float)cnt, 1.0f);
        }
        out4[(size_t)w * H4 + h] = acc;
        cur += cnt;
    }
}

extern "C" void kernel_launch(void* const* d_in, const int* in_sizes, int n_in,
                              void* d_out, int out_size, void* d_ws, size_t ws_size,
                              hipStream_t stream) {
    const float* x  = (const float*)d_in[0];
    const int* seg  = (const int*)d_in[1];
    int n_tokens    = in_sizes[1];          // B*S = 32768
    int W           = out_size / H_DIM;     // num_segments = 8192

    int grid = (W + WPB - 1) / WPB;
    WordPooling_fused_kernel<<<grid, H4, 0, stream>>>(x, seg, n_tokens, W, (float*)d_out);
}

// Round 6
// 30.442 us; speedup vs baseline: 1.0352x; 1.0094x over previous
//
#include <hip/hip_runtime.h>

#define H_DIM 1024
#define H4 (H_DIM / 4)   // float4 elements per row = 256
#define WPB 8            // words per block

typedef float f32x4 __attribute__((ext_vector_type(4)));

// 1024 blocks x 256 threads. Each block owns WPB=8 consecutive words; each
// thread owns one float4 (16B) slot of the H=1024 row. Span discovery:
// gallop-from-proportional-guess binary search for the block's first word,
// then wave-parallel span counting via one 64-lane seg load + __ballot
// (scalar-scan fallback if the 8 words span >64 tokens).
// Loads: CACHED (R5: cached loads beat nt loads by ~2.5% — harness reset()
// fills evict L3 between replays, so reads stream from HBM either way, but
// nt hints cost a little on the read path).
// Stores: NON-TEMPORAL (out is write-once, never re-read; avoid write-
// allocating 32 MB = 100% of per-XCD L2, which churns the read stream).
__global__ void __launch_bounds__(256)
WordPooling_fused_kernel(const float* __restrict__ x,
                         const int* __restrict__ seg,
                         int n_tokens, int W,
                         float* __restrict__ out) {
    int w0 = blockIdx.x * WPB;
    int h = threadIdx.x;
    int lane = threadIdx.x & 63;

    // ---- st = lower_bound(seg, w0): first token with seg[t] >= w0 ----
    int st = 0;
    if (w0 > 0) {
        int g = (int)((long long)w0 * n_tokens / W);   // proportional guess
        if (g > n_tokens - 1) g = n_tokens - 1;
        int lo, hi;  // invariant: seg[lo] < w0 (lo==-1), seg[hi] >= w0 (hi==n)
        if (seg[g] >= w0) {
            int step = 1;
            while (step <= g && seg[g - step] >= w0) step <<= 1;
            lo = (step <= g) ? g - step : -1;
            hi = g - (step >> 1);
        } else {
            int step = 1;
            while (g + step < n_tokens && seg[g + step] < w0) step <<= 1;
            lo = g + (step >> 1);
            hi = (g + step < n_tokens) ? g + step : n_tokens;
        }
        while (hi - lo > 1) {
            int mid = (lo + hi) >> 1;
            if (seg[mid] < w0) lo = mid; else hi = mid;
        }
        st = hi;
    }

    int wlast = w0 + WPB - 1;
    if (wlast > W - 1) wlast = W - 1;

    // ---- wave-parallel span counts over a 64-token window ----
    int idx = st + lane;
    int sv = (idx < n_tokens) ? seg[idx] : 0x7FFFFFFF;
    bool windowed = (__ballot(sv > wlast) != 0ULL);  // all owned tokens inside window

    const f32x4* x4 = (const f32x4*)x;
    f32x4* out4 = (f32x4*)out;

    int cur = st;
    for (int w = w0; w <= wlast; ++w) {
        int cnt;
        if (windowed) {
            cnt = (int)__popcll(__ballot(sv == w));
        } else {
            cnt = 0;  // generic fallback: dependent scalar scan
            while (cur + cnt < n_tokens && seg[cur + cnt] == w) ++cnt;
        }
        const f32x4* p = x4 + (size_t)cur * H4 + h;
        f32x4 acc;
        if (cnt == 4) {
            f32x4 v0 = p[0];
            f32x4 v1 = p[H4];
            f32x4 v2 = p[2 * H4];
            f32x4 v3 = p[3 * H4];
            acc = (((v0 + v1) + v2) + v3) * 0.25f;
        } else {
            acc = (f32x4)(0.0f);
            for (int i = 0; i < cnt; ++i)
                acc += p[(size_t)i * H4];
            acc *= 1.0f / fmaxf((float)cnt, 1.0f);
        }
        __builtin_nontemporal_store(acc, out4 + (size_t)w * H4 + h);
        cur += cnt;
    }
}

extern "C" void kernel_launch(void* const* d_in, const int* in_sizes, int n_in,
                              void* d_out, int out_size, void* d_ws, size_t ws_size,
                              hipStream_t stream) {
    const float* x  = (const float*)d_in[0];
    const int* seg  = (const int*)d_in[1];
    int n_tokens    = in_sizes[1];          // B*S = 32768
    int W           = out_size / H_DIM;     // num_segments = 8192

    int grid = (W + WPB - 1) / WPB;
    WordPooling_fused_kernel<<<grid, H4, 0, stream>>>(x, seg, n_tokens, W, (float*)d_out);
}